// Round 4
// baseline (274.710 us; speedup 1.0000x reference)
//
#include <hip/hip_runtime.h>
#include <math.h>

// Router: scores = x @ emb^T [32768 x 64] fp32, top-2 + 2-way softmax scatter.
//
// lane = TOKEN (64 tokens/block), wave w owns experts [16w,16w+16).
// emb streams via UNIFORM-ADDRESS VECTOR loads (global_load_dwordx4, all lanes
// same address -> 1 L1 line, broadcast return). NOT scalarized: expert group is
// computed from tid>>6 (divergent to the compiler) -- round 3's readfirstlane
// forced s_load streaming, which choked on SGPR pressure + K$ thrash (VALU 12%).
// x staged via global_load_lds (linear dest, XOR-pre-swizzled source), read as
// 16 lane-varying ds_read_b128 per wave-chunk (0 conflicts measured).

constexpr int HDIM = 1024;
constexpr int NEXP = 64;
constexpr int TPB  = 64;            // tokens per block
constexpr int BK   = 64;            // k per chunk
constexpr int NQ   = BK / 4;        // 16 quads
constexpr int NTHREADS = 256;
constexpr int NCHUNK = HDIM / BK;   // 16

__global__ __launch_bounds__(NTHREADS, 4)
void router_kernel(const float* __restrict__ x,
                   const float* __restrict__ emb,
                   float* __restrict__ out)
{
    __shared__ float4 xs[2][TPB][NQ];   // 32 KiB, x[token][quad^(token&15)]
    __shared__ float4 cand[4][TPB];     // 4 KiB, per-wave top-2 candidates

    const int tid  = threadIdx.x;
    const int lane = tid & 63;          // token-in-block
    const int w    = tid >> 6;          // expert group -- KEEP DIVERGENT (no
                                        // readfirstlane) so emb loads stay VMEM
    const int tok0 = blockIdx.x * TPB;
    const int sw   = lane & 15;

    // Stage chunk C of x into buffer P. Dest is wave-linear (base + lane*16);
    // the read-side XOR swizzle is folded into the per-lane GLOBAL source.
#define STAGE(P, C)                                                            \
    do {                                                                       \
        _Pragma("unroll")                                                      \
        for (int j = 0; j < 4; ++j) {                                          \
            const int g = j * 256 + tid;                                       \
            const int r = g >> 4, q = g & 15;                                  \
            const float* src = x + (size_t)(tok0 + r) * HDIM + (C) * BK        \
                                 + ((q ^ (r & 15)) * 4);                       \
            __builtin_amdgcn_global_load_lds(                                  \
                (const __attribute__((address_space(1))) void*)src,            \
                (__attribute__((address_space(3))) void*)&xs[P][r][q],         \
                16, 0, 0);                                                     \
        }                                                                      \
    } while (0)

    float acc[16];
#pragma unroll
    for (int i = 0; i < 16; ++i) acc[i] = 0.f;

    STAGE(0, 0);
    int p = 0;

#pragma unroll 1
    for (int c = 0; c < NCHUNK; ++c) {
        __syncthreads();                       // chunk c staged
        if (c + 1 < NCHUNK) STAGE(p ^ 1, c + 1);

#pragma unroll
        for (int kb = 0; kb < 4; ++kb) {
            // this lane's token: 16 k-values into regs (4 swizzled b128 reads)
            float4 xq[4];
#pragma unroll
            for (int i = 0; i < 4; ++i) xq[i] = xs[p][lane][(4 * kb + i) ^ sw];
            const float* xf = (const float*)xq;

            // emb: uniform-address float4 VMEM loads, 4 independent acc chains
#pragma unroll 4
            for (int e = 0; e < 16; ++e) {
                const float4* ep = (const float4*)(emb
                                     + (size_t)(16 * w + e) * HDIM
                                     + c * BK + kb * 16);
                const float4 e0 = ep[0], e1 = ep[1], e2 = ep[2], e3 = ep[3];
                float a = acc[e];
                a = fmaf(e0.x, xf[0],  a); a = fmaf(e0.y, xf[1],  a);
                a = fmaf(e0.z, xf[2],  a); a = fmaf(e0.w, xf[3],  a);
                a = fmaf(e1.x, xf[4],  a); a = fmaf(e1.y, xf[5],  a);
                a = fmaf(e1.z, xf[6],  a); a = fmaf(e1.w, xf[7],  a);
                a = fmaf(e2.x, xf[8],  a); a = fmaf(e2.y, xf[9],  a);
                a = fmaf(e2.z, xf[10], a); a = fmaf(e2.w, xf[11], a);
                a = fmaf(e3.x, xf[12], a); a = fmaf(e3.y, xf[13], a);
                a = fmaf(e3.z, xf[14], a); a = fmaf(e3.w, xf[15], a);
                acc[e] = a;
            }
        }
        p ^= 1;
    }

    // ---- per-lane local top-2 over this wave's 16 experts (register-only) ----
    float v1 = acc[0], v2 = -INFINITY;
    int   j1 = 0,      j2 = 0;
#pragma unroll
    for (int j = 1; j < 16; ++j) {
        if (acc[j] > v1)      { v2 = v1; j2 = j1; v1 = acc[j]; j1 = j; }
        else if (acc[j] > v2) { v2 = acc[j]; j2 = j; }
    }
    float4 cd;
    cd.x = v1; cd.y = __int_as_float(16 * w + j1);
    cd.z = v2; cd.w = __int_as_float(16 * w + j2);
    cand[w][lane] = cd;
    __syncthreads();

    // ---- merge 4 waves' candidates, ascending expert order (tie: lowest idx) ----
    float V1 = -INFINITY, V2 = -INFINITY;
    int   E1 = 0,         E2 = 0;
#pragma unroll
    for (int ww = 0; ww < 4; ++ww) {
        const float4 q = cand[ww][lane];
        const float a = q.x; const int ea = __float_as_int(q.y);
        const float b = q.z; const int eb = __float_as_int(q.w);
        if (a > V1)      { V2 = V1; E2 = E1; V1 = a; E1 = ea; }
        else if (a > V2) { V2 = a; E2 = ea; }
        if (b > V1)      { V2 = V1; E2 = E1; V1 = b; E1 = eb; }
        else if (b > V2) { V2 = b; E2 = eb; }
    }
    const float et = expf(V2 - V1);
    const float p1 = 1.f / (1.f + et);
    const float p2 = et / (1.f + et);

    // ---- build output rows in LDS (reuse xs[0]), then coalesced store ----
    float4* rb = (float4*)&xs[0][0][0];        // [64 tokens][16 quads], swizzled
#pragma unroll
    for (int qq = 0; qq < 4; ++qq) {
        const int q = 4 * w + qq;              // quad = experts 4q..4q+3
        float4 o;
        float* of = (float*)&o;
#pragma unroll
        for (int i = 0; i < 4; ++i) {
            const int e = 4 * q + i;
            of[i] = (e == E1) ? p1 : (e == E2) ? p2 : 0.f;
        }
        rb[lane * 16 + (q ^ sw)] = o;
    }
    __syncthreads();

    const int t  = tid >> 2;
    const int qb = (tid & 3) * 4;
#pragma unroll
    for (int i = 0; i < 4; ++i) {
        const int q = qb + i;
        const float4 o = rb[t * 16 + (q ^ (t & 15))];
        *(float4*)(out + (size_t)(tok0 + t) * NEXP + q * 4) = o;
    }
#undef STAGE
}

extern "C" void kernel_launch(void* const* d_in, const int* in_sizes, int n_in,
                              void* d_out, int out_size, void* d_ws, size_t ws_size,
                              hipStream_t stream)
{
    const float* x   = (const float*)d_in[0];
    const float* emb = (const float*)d_in[1];
    float* out = (float*)d_out;

    const int n_tokens = in_sizes[0] / HDIM;     // 32768
    const int nblocks  = n_tokens / TPB;         // 512

    router_kernel<<<nblocks, NTHREADS, 0, stream>>>(x, emb, out);
}